// Round 16
// baseline (887.812 us; speedup 1.0000x reference)
//
#include <hip/hip_runtime.h>

// ConvLSTM cell, MI355X. Implicit-GEMM over concat(x,h) channels, bf16 MFMA
// 32x32x16, fused in-register LSTM epilogue.
// R16: R15 with __launch_bounds__(256, 4) — force arch VGPRs <= 64 so
// total/wave = 64 + 64 AGPR = 128 -> 4 waves/SIMD (16/CU). LDS already slim
// (2 x 10368 B). Single-variable occupancy experiment vs R15.

typedef __bf16 bf16x8 __attribute__((ext_vector_type(8)));
typedef float f32x16 __attribute__((ext_vector_type(16)));

#define SUB_B    10368u                 // 324 positions * 32 B (16 ch bf16)
#define WT_BYTES 9441280u               // 9,437,184 + align slack
#define OUT_HALF 16777216u              // B*CH*S

__device__ inline void gload_lds16(const void* g, void* l) {
    __builtin_amdgcn_global_load_lds(
        (const __attribute__((address_space(1))) void*)g,
        (__attribute__((address_space(3))) void*)l, 16, 0, 0);
}

// ---------------------------------------------------------------------------
// P1a: x,h (NCHW fp32) -> per-(b,ibk) TWO half-K sub-planes (16 ch each),
// packed 10368 B, zero border, swizzled: byte = (p*32 + ofs) ^ ((p&4)<<2).
__global__ __launch_bounds__(256) void xh_transform(
    const float* __restrict__ x, const float* __restrict__ hh,
    unsigned char* __restrict__ xh)
{
    int blk = blockIdx.x;              // b*16 + ibk
    int b = blk >> 4, ibk = blk & 15;
    const float* src = (ibk < 8) ? (x  + ((size_t)(b*256 + ibk*32)) * 256)
                                 : (hh + ((size_t)(b*256 + (ibk-8)*32)) * 256);
    int t = threadIdx.x;               // t == spatial s
    uint32_t w[16];
#pragma unroll
    for (int i = 0; i < 16; ++i) {
        __bf16 lo = (__bf16)src[(size_t)(2*i  )*256 + t];
        __bf16 hi = (__bf16)src[(size_t)(2*i+1)*256 + t];
        w[i] = (uint32_t)__builtin_bit_cast(unsigned short, lo)
             | ((uint32_t)__builtin_bit_cast(unsigned short, hi) << 16);
    }
    int p = ((t >> 4) + 1)*18 + (t & 15) + 1;      // interior position
    uint32_t key  = ((uint32_t)p & 4u) << 2;
    uint32_t base = (uint32_t)p * 32u;
#pragma unroll
    for (int hb = 0; hb < 2; ++hb) {
        unsigned char* sp = xh + (size_t)(blk*2 + hb) * SUB_B;
        *(uint4*)(sp + ((base +  0u) ^ key)) =
            uint4{w[8*hb+0], w[8*hb+1], w[8*hb+2], w[8*hb+3]};
        *(uint4*)(sp + ((base + 16u) ^ key)) =
            uint4{w[8*hb+4], w[8*hb+5], w[8*hb+6], w[8*hb+7]};
    }
    // zero the 68 border positions (rows 0,17; cols 0,17) in both halves
    if (t < 68) {
        int pb;
        if      (t < 18) pb = t;                   // row 0
        else if (t < 36) pb = 17*18 + (t - 18);    // row 17
        else if (t < 52) pb = (t - 35)*18;         // rows 1..16, col 0
        else             pb = (t - 51)*18 + 17;    // rows 1..16, col 17
        uint32_t kb = ((uint32_t)pb & 4u) << 2;
        uint32_t bb = (uint32_t)pb * 32u;
        uint4 z{0u,0u,0u,0u};
#pragma unroll
        for (int hb = 0; hb < 2; ++hb) {
            unsigned char* sp = xh + (size_t)(blk*2 + hb) * SUB_B;
            *(uint4*)(sp + ((bb +  0u) ^ kb)) = z;
            *(uint4*)(sp + ((bb + 16u) ^ kb)) = z;
        }
    }
}

// ---------------------------------------------------------------------------
// P1b: Wx,Wh (OIHW fp32) -> Wt bf16 in A-fragment order.
// chunk = (((cbnh*16 + ibk)*2 + half)*9 + pos)*2 + f ; 64 lanes x 8 bf16.
__global__ __launch_bounds__(256) void w_transform(
    const float* __restrict__ Wx, const float* __restrict__ Wh,
    __bf16* __restrict__ Wt)
{
    int idx  = blockIdx.x * 256 + threadIdx.x;   // 589824 total
    int lane = idx & 63;
    int chunk = idx >> 6;                        // 9216 chunks
    int f    = chunk & 1;
    int q    = chunk >> 1;
    int pos  = q % 9;
    int r    = q / 9;
    int half = r & 1;
    int ibk  = (r >> 1) & 15;
    int cbnh = r >> 5;
    int nh = cbnh & 1, cb = cbnh >> 1;
    int row = lane & 31, hl = lane >> 5;
    int gate = row & 3, ch8 = row >> 2;
    int oc  = gate*256 + cb*32 + (nh*2 + f)*8 + ch8;
    int ic0 = ibk*32 + half*16 + hl*8;
    bf16x8 v;
#pragma unroll
    for (int j = 0; j < 8; ++j) {
        int ic = ic0 + j;
        float w = (ic < 256) ? Wx[((size_t)oc*256 + ic      )*9 + pos]
                             : Wh[((size_t)oc*256 + (ic-256))*9 + pos];
        v[j] = (__bf16)w;
    }
    *(bf16x8*)(Wt + (size_t)chunk*512 + (size_t)lane*8) = v;
}

// ---------------------------------------------------------------------------
// Main. Block = (b, nh, cb): 256m x 64oc'. 4 waves, each 64m x 64oc:
// acc[2][2] f32x16 = 64 AGPR. 32 sub-buffers x 9 phases x 4 MFMA.
__global__ __launch_bounds__(256, 4) void convlstm_main(
    const unsigned char* __restrict__ xh, const unsigned char* __restrict__ Wtb,
    const float* __restrict__ bh,  const float* __restrict__ cin,
    const float* __restrict__ Wci, const float* __restrict__ Wcf,
    const float* __restrict__ Wco, float* __restrict__ out)
{
    int bid = blockIdx.x;               // b*16 + nh*8 + cb
    int cb  = bid & 7;
    int nh  = (bid >> 3) & 1;
    int b   = bid >> 4;
    int tid = threadIdx.x;
    int lane = tid & 63, wv = tid >> 6;
    int l31 = lane & 31, hl = lane >> 5;

    __shared__ __align__(16) unsigned char lds[2][10368];

    // accumulators init with bias bh[oc]
    f32x16 acc[2][2];
#pragma unroll
    for (int f = 0; f < 2; ++f) {
        int fg = nh*2 + f;
        f32x16 v;
#pragma unroll
        for (int r = 0; r < 16; ++r) {
            int gate = r & 3, q = r >> 2;
            v[r] = bh[gate*256 + cb*32 + fg*8 + 2*q + hl];
        }
        acc[0][f] = v; acc[1][f] = v;
    }

    const unsigned char* subs = xh + (size_t)b * (32u * SUB_B);

// Stage one 10368-B sub-plane: waves 0-2 take 3 KB each, wave 3 takes the
// last 1 KB + masked 128-B tail (8 lanes).
#define STAGE(BUF, SRC)                                                      \
    if (wv < 3) {                                                            \
        _Pragma("unroll")                                                    \
        for (int j = 0; j < 3; ++j)                                          \
            gload_lds16((SRC) + (size_t)(wv*3072 + j*1024 + lane*16),        \
                        &lds[BUF][wv*3072 + j*1024 + lane*16]);              \
    } else {                                                                 \
        gload_lds16((SRC) + (size_t)(9216 + lane*16),                        \
                    &lds[BUF][9216 + lane*16]);                              \
        if (lane < 8)                                                        \
            gload_lds16((SRC) + (size_t)(10240 + lane*16),                   \
                        &lds[BUF][10240 + lane*16]);                         \
    }

    // initial stage: sub-buffer 0 into LDS buffer 0
    STAGE(0, subs)

    // B address bases: m0 = wv*64 + l31 (m1 = m0+32 -> p+36).
    // byte(p) = (p*32 + hl*16 + buf*10368) ^ ((p&4)<<2); addr1 = (addr0+1152)^16.
    int m0 = wv*64 + l31;
    int pbase0 = (m0 >> 4)*18 + (m0 & 15);
    uint32_t pk0 = (uint32_t)pbase0*32u + (uint32_t)(hl*16);
    const char* ldsbase = (const char*)&lds[0][0];

    // A pointer: uniform base + lane*16; per-phase offsets literal.
    const unsigned char* wptr = Wtb + (size_t)(cb*2 + nh)*589824u
                                    + (size_t)(lane*16);
    const unsigned char* srcn = subs + SUB_B;   // next sub-plane to stage

    bf16x8 A[2][2], Bb[2][2];
    // A prologue: (sub0, p0) into A[0]
    A[0][0] = *(const bf16x8*)(wptr + 0);
    A[0][1] = *(const bf16x8*)(wptr + 1024);

    __syncthreads();   // initial DMA drained (full), waves joined

// One sub-buffer. PAR literal 0/1: LDS buffer = PAR, ping = (p+PAR)&1.
// p8 A-prefetch (tp=9 -> wptr+18432 = next sub) goes to A[PAR^1]; next
// sub-buffer (parity PAR^1) consumes p0 from A[PAR^1]. LASTF gates DMA.
#define SUBBUF(PAR, LASTF)                                                   \
    {                                                                        \
        {   /* B prologue: pos 0, dist-0 (data valid only after barrier) */  \
            uint32_t p0a = (pk0 + (PAR)*10368u)                              \
                           ^ (((uint32_t)pbase0 & 4u) << 2);                 \
            uint32_t p1a = (p0a + 1152u) ^ 16u;                              \
            Bb[(PAR)][0] = *(const bf16x8*)(ldsbase + p0a);                  \
            Bb[(PAR)][1] = *(const bf16x8*)(ldsbase + p1a);                  \
        }                                                                    \
        _Pragma("unroll")                                                    \
        for (int p = 0; p < 9; ++p) {                                        \
            const int ping = (p + (PAR)) & 1;                                \
            {   /* A prefetch dist-1 (tp==9 reads next sub-buffer) */        \
                const int aoff = (p + 1) * 2048;                             \
                A[ping ^ 1][0] = *(const bf16x8*)(wptr + aoff);              \
                A[ping ^ 1][1] = *(const bf16x8*)(wptr + aoff + 1024);       \
            }                                                                \
            if (p == 1 && !(LASTF)) { STAGE((PAR) ^ 1, srcn) }               \
            if (p < 8) {   /* B prefetch dist-1 */                           \
                const int np = p + 1;                                        \
                const uint32_t D = (uint32_t)((np/3)*18 + (np%3));           \
                uint32_t pp = (uint32_t)pbase0 + D;                          \
                uint32_t a0 = (pk0 + D*32u + (PAR)*10368u)                   \
                              ^ ((pp & 4u) << 2);                            \
                uint32_t a1 = (a0 + 1152u) ^ 16u;                            \
                Bb[ping ^ 1][0] = *(const bf16x8*)(ldsbase + a0);            \
                Bb[ping ^ 1][1] = *(const bf16x8*)(ldsbase + a1);            \
            }                                                                \
            __builtin_amdgcn_s_setprio(1);                                   \
            acc[0][0] = __builtin_amdgcn_mfma_f32_32x32x16_bf16(A[ping][0], Bb[ping][0], acc[0][0], 0, 0, 0); \
            acc[0][1] = __builtin_amdgcn_mfma_f32_32x32x16_bf16(A[ping][1], Bb[ping][0], acc[0][1], 0, 0, 0); \
            acc[1][0] = __builtin_amdgcn_mfma_f32_32x32x16_bf16(A[ping][0], Bb[ping][1], acc[1][0], 0, 0, 0); \
            acc[1][1] = __builtin_amdgcn_mfma_f32_32x32x16_bf16(A[ping][1], Bb[ping][1], acc[1][1], 0, 0, 0); \
            __builtin_amdgcn_s_setprio(0);                                   \
        }                                                                    \
        wptr += 18432;                                                       \
        srcn += SUB_B;                                                       \
        /* counted barrier: 4 newest vmem (p7/p8 A prefetches) in flight; */ \
        /* DMA + older A loads complete. */                                  \
        asm volatile("s_waitcnt vmcnt(4) lgkmcnt(0)" ::: "memory");          \
        __builtin_amdgcn_s_barrier();                                        \
        __builtin_amdgcn_sched_barrier(0);                                   \
    }

    for (int sb2 = 0; sb2 < 16; ++sb2) {
        SUBBUF(0, false)
        SUBBUF(1, (sb2 == 15))
    }
#undef SUBBUF
#undef STAGE

    // fused LSTM epilogue. col = l31 (m), r = 4*q + gate,
    // ch = cb*32 + fg*8 + 2*q + hl.
    float* outh = out;
    float* outc = out + (size_t)OUT_HALF;
    const size_t bOff = (size_t)b * (256*256);
#pragma unroll
    for (int mf = 0; mf < 2; ++mf) {
        int m = wv*64 + mf*32 + l31;
#pragma unroll
        for (int f = 0; f < 2; ++f) {
            int fg = nh*2 + f;
#pragma unroll
            for (int q = 0; q < 4; ++q) {
                int ch = cb*32 + fg*8 + 2*q + hl;
                size_t pidx = (size_t)ch*256 + (size_t)m;
                size_t idx  = bOff + pidx;
                float cv = cin[idx];
                float pi = acc[mf][f][4*q+0];
                float pf = acc[mf][f][4*q+1];
                float pc = acc[mf][f][4*q+2];
                float po = acc[mf][f][4*q+3];
                float it = 1.f/(1.f + __expf(-(pi + Wci[pidx]*cv)));
                float ft = 1.f/(1.f + __expf(-(pf + Wcf[pidx]*cv)));
                float tc = 1.f - 2.f/(1.f + __expf(2.f*pc));
                float ct = ft*cv + it*tc;
                float ot = 1.f/(1.f + __expf(-(po + Wco[pidx]*ct)));
                float th = 1.f - 2.f/(1.f + __expf(2.f*ct));
                outh[idx] = ot*th;
                outc[idx] = ct;
            }
        }
    }
}

// ---------------------------------------------------------------------------
extern "C" void kernel_launch(void* const* d_in, const int* in_sizes, int n_in,
                              void* d_out, int out_size, void* d_ws, size_t ws_size,
                              hipStream_t stream)
{
    const float* x   = (const float*)d_in[0];
    const float* h   = (const float*)d_in[1];
    const float* c   = (const float*)d_in[2];
    const float* Wx  = (const float*)d_in[3];
    const float* Wh  = (const float*)d_in[4];
    const float* bh  = (const float*)d_in[5];
    const float* Wci = (const float*)d_in[6];
    const float* Wcf = (const float*)d_in[7];
    const float* Wco = (const float*)d_in[8];
    float* out = (float*)d_out;

    // Wt FIRST so the final sub-buffer's dummy A prefetch overrun lands in
    // the xh region (valid memory).
    unsigned char* wtb = (unsigned char*)d_ws;       // 9.44 MB
    unsigned char* xh  = wtb + (size_t)WT_BYTES;     // 8192 x 10368 B

    hipLaunchKernelGGL(xh_transform, dim3(4096), dim3(256), 0, stream, x, h, xh);
    hipLaunchKernelGGL(w_transform,  dim3(2304), dim3(256), 0, stream,
                       Wx, Wh, (__bf16*)wtb);
    hipLaunchKernelGGL(convlstm_main, dim3(4096), dim3(256), 0, stream,
                       xh, wtb, bh, c, Wci, Wcf, Wco, out);
}

// Round 17
// 632.794 us; speedup vs baseline: 1.4030x; 1.4030x over previous
//
#include <hip/hip_runtime.h>

// ConvLSTM cell, MI355X. Implicit-GEMM over concat(x,h) channels, bf16 MFMA
// 32x32x16, fused in-register LSTM epilogue.
// R17: R13 + B dist-2 (3-slot rotation, +8 VGPR within the 3-wave budget).
// R13 base: Wt relayout -> literal-offset A loads; precomputed B LDS
// addresses; A dist-2 (%3 slots); DMA at phase 1; counted vmcnt(4) barrier;
// add-based buffer flip; last ibk peeled.

typedef __bf16 bf16x8 __attribute__((ext_vector_type(8)));
typedef float f32x16 __attribute__((ext_vector_type(16)));

#define PLANE_B  20736u                 // 324 positions * 64 B (18x18x32 bf16)
#define XH_BYTES (4096u * PLANE_B)      // 256 b * 16 icblk planes
#define OUT_HALF 16777216u              // B*CH*S

__device__ inline void gload_lds16(const void* g, void* l) {
    __builtin_amdgcn_global_load_lds(
        (const __attribute__((address_space(1))) void*)g,
        (__attribute__((address_space(3))) void*)l, 16, 0, 0);
}

// ---------------------------------------------------------------------------
// P1a: x,h (NCHW fp32) -> padded swizzled bf16 planes.
// addr = (p*64 + ofs) ^ ((p&7)<<4)  (bijective; same formula on read).
__global__ __launch_bounds__(256) void xh_transform(
    const float* __restrict__ x, const float* __restrict__ hh,
    unsigned char* __restrict__ xh)
{
    int blk = blockIdx.x;              // b*16 + ibk
    int b = blk >> 4, ibk = blk & 15;
    const float* src = (ibk < 8) ? (x  + ((size_t)(b*256 + ibk*32)) * 256)
                                 : (hh + ((size_t)(b*256 + (ibk-8)*32)) * 256);
    int t = threadIdx.x;               // t == spatial s
    uint32_t w[16];
#pragma unroll
    for (int i = 0; i < 16; ++i) {
        __bf16 lo = (__bf16)src[(size_t)(2*i  )*256 + t];
        __bf16 hi = (__bf16)src[(size_t)(2*i+1)*256 + t];
        w[i] = (uint32_t)__builtin_bit_cast(unsigned short, lo)
             | ((uint32_t)__builtin_bit_cast(unsigned short, hi) << 16);
    }
    unsigned char* plane = xh + (size_t)blk * PLANE_B;
    int p = ((t >> 4) + 1)*18 + (t & 15) + 1;      // interior position
    uint32_t key  = (uint32_t)(p & 7) << 4;
    uint32_t base = (uint32_t)p * 64u;
#pragma unroll
    for (int k = 0; k < 4; ++k)
        *(uint4*)(plane + ((base + 16u*k) ^ key)) =
            uint4{w[4*k], w[4*k+1], w[4*k+2], w[4*k+3]};
    // zero the 68 border positions (rows 0,17; cols 0,17)
    if (t < 68) {
        int pb;
        if      (t < 18) pb = t;                   // row 0
        else if (t < 36) pb = 17*18 + (t - 18);    // row 17
        else if (t < 52) pb = (t - 35)*18;         // rows 1..16, col 0
        else             pb = (t - 51)*18 + 17;    // rows 1..16, col 17
        uint32_t kb = (uint32_t)(pb & 7) << 4;
        uint32_t bb = (uint32_t)pb * 64u;
        uint4 z{0u,0u,0u,0u};
#pragma unroll
        for (int k = 0; k < 4; ++k)
            *(uint4*)(plane + ((bb + 16u*k) ^ kb)) = z;
    }
}

// ---------------------------------------------------------------------------
// P1b: Wx,Wh (OIHW fp32) -> Wt bf16 in A-fragment order.
// chunk = ((cbnh*16 + ibk)*9 + pos)*4 + half*2 + f ; 64 lanes x 8 bf16 each.
__global__ __launch_bounds__(256) void w_transform(
    const float* __restrict__ Wx, const float* __restrict__ Wh,
    __bf16* __restrict__ Wt)
{
    int idx  = blockIdx.x * 256 + threadIdx.x;   // 589824 total
    int lane = idx & 63;
    int chunk = idx >> 6;                        // 9216 chunks
    int f     = chunk & 1;
    int half  = (chunk >> 1) & 1;
    int pos   = (chunk >> 2) % 9;                // ky*3+kx
    int rest  = (chunk >> 2) / 9;                // 0..255
    int ibk   = rest & 15;
    int cbnh  = rest >> 4;
    int nh = cbnh & 1, cb = cbnh >> 1;
    int row = lane & 31, hl = lane >> 5;
    int gate = row & 3, ch8 = row >> 2;
    int oc  = gate*256 + cb*32 + (nh*2 + f)*8 + ch8;
    int ic0 = ibk*32 + half*16 + hl*8;
    bf16x8 v;
#pragma unroll
    for (int j = 0; j < 8; ++j) {
        int ic = ic0 + j;
        float w = (ic < 256) ? Wx[((size_t)oc*256 + ic      )*9 + pos]
                             : Wh[((size_t)oc*256 + (ic-256))*9 + pos];
        v[j] = (__bf16)w;
    }
    *(bf16x8*)(Wt + (size_t)chunk*512 + (size_t)lane*8) = v;
}

// ---------------------------------------------------------------------------
// Main. Block = (b, nh, cb): 256m x 64oc'. 4 waves, each 64m x 64oc:
// acc[2][2] f32x16 = 64 AGPR. 18 phases/ibk; A dist-2 (%3), B dist-2 (%3),
// DMA at phase 1, counted-vmcnt barrier. Last ibk peeled.
__global__ __launch_bounds__(256, 2) void convlstm_main(
    const unsigned char* __restrict__ xh, const __bf16* __restrict__ Wt,
    const float* __restrict__ bh,  const float* __restrict__ cin,
    const float* __restrict__ Wci, const float* __restrict__ Wcf,
    const float* __restrict__ Wco, float* __restrict__ out)
{
    int bid = blockIdx.x;               // b*16 + nh*8 + cb
    int cb  = bid & 7;
    int nh  = (bid >> 3) & 1;
    int b   = bid >> 4;
    int tid = threadIdx.x;
    int lane = tid & 63, wv = tid >> 6;
    int l31 = lane & 31, hl = lane >> 5;

    __shared__ __align__(16) unsigned char lds[2][24576];

    // accumulators init with bias bh[oc]
    f32x16 acc[2][2];
#pragma unroll
    for (int f = 0; f < 2; ++f) {
        int fg = nh*2 + f;
        f32x16 v;
#pragma unroll
        for (int r = 0; r < 16; ++r) {
            int gate = r & 3, q = r >> 2;
            v[r] = bh[gate*256 + cb*32 + fg*8 + 2*q + hl];
        }
        acc[0][f] = v; acc[1][f] = v;
    }

    const unsigned char* planes = xh + (size_t)b * (16u * PLANE_B);

    // stage plane 0 into buffer 0 (linear DMA; plane pre-padded+swizzled)
#pragma unroll
    for (int k = 0; k < 6; ++k)
        gload_lds16(planes + (size_t)(wv*6 + k)*1024u + (size_t)lane*16u,
                    &lds[0][(wv*6 + k)*1024 + lane*16]);

    // B LDS addresses: 9 pos x 2 m-frags, half=0, buffer 0.
    // byte(p,half) = (p*64 + hl*16 + half*32) ^ ((p&7)<<4)
    //              = baddr ^ (half*32)   [bit5 of pre-XOR base is 0]
    int m0 = wv*64 + l31, m1 = m0 + 32;
    int pb0 = (m0 >> 4)*18 + (m0 & 15);
    int pb1 = (m1 >> 4)*18 + (m1 & 15);
    const uint32_t kbase = (uint32_t)(hl*16);
    uint32_t baddr[9][2];
#pragma unroll
    for (int pos = 0; pos < 9; ++pos) {
        int d = (pos/3)*18 + (pos%3);
        int p0 = pb0 + d, p1 = pb1 + d;
        baddr[pos][0] = ((uint32_t)p0*64u + kbase) ^ (((uint32_t)(p0 & 7)) << 4);
        baddr[pos][1] = ((uint32_t)p1*64u + kbase) ^ (((uint32_t)(p1 & 7)) << 4);
    }
    const char* lds0 = (const char*)&lds[0][0];

    // A base: wave-uniform + lane; per-phase offsets are literals.
    // addr_e(ibk,pos,half,f) = cbnh*294912 + ibk*18432 + pos*2048
    //                        + half*1024 + f*512 + lane*8
    const __bf16* abase = Wt + (size_t)(cb*2 + nh)*294912u + (size_t)lane*8;

    // A prologue: slots 0,1 = (ibk0, ph0), (ibk0, ph1)
    bf16x8 A[3][2];
    A[0][0] = *(const bf16x8*)(abase + 0);
    A[0][1] = *(const bf16x8*)(abase + 512);
    A[1][0] = *(const bf16x8*)(abase + 1024);
    A[1][1] = *(const bf16x8*)(abase + 1536);

    __syncthreads();   // prologue: full drain once (DMA + joins waves)

// One ibk body. LAST is a literal: gates the DMA and the cross-ibk prefetch.
// B dist-2: slots %3; prologue fills slots 0,1 (ph0 = pos0/half0, ph1 =
// pos0/half1 = baddr^32); in-phase prefetch reads ph p+2 for p<16.
#define IBK_PHASES(LAST)                                                     \
    {                                                                        \
        bf16x8 Bb[3][2];                                                     \
        Bb[0][0] = *(const bf16x8*)(lds0 + baddr[0][0]);                     \
        Bb[0][1] = *(const bf16x8*)(lds0 + baddr[0][1]);                     \
        Bb[1][0] = *(const bf16x8*)(lds0 + (baddr[0][0] ^ 32u));             \
        Bb[1][1] = *(const bf16x8*)(lds0 + (baddr[0][1] ^ 32u));             \
        _Pragma("unroll")                                                    \
        for (int p = 0; p < 18; ++p) {                                       \
            /* A prefetch dist 2 into slot (p+2)%3; crosses ibk at p>=16 */  \
            {                                                                \
                const int tp = p + 2;                                        \
                const int xo = (tp < 18) ? 0 : ((LAST) ? -18432 : 0);        \
                const int off = ((tp < 18)                                   \
                    ? ((tp>>1)*2048 + (tp&1)*1024)                           \
                    : (18432 + (((tp-18)>>1)*2048 + ((tp-18)&1)*1024))) + xo;\
                A[(p+2)%3][0] = *(const bf16x8*)(abase + off);               \
                A[(p+2)%3][1] = *(const bf16x8*)(abase + off + 512);         \
            }                                                                \
            if (p == 1 && !(LAST)) {                                         \
                const unsigned char* np_ = planes + (size_t)(ibk+1)*PLANE_B; \
                _Pragma("unroll")                                            \
                for (int k = 0; k < 6; ++k)                                  \
                    gload_lds16(np_ + (size_t)(wv*6 + k)*1024u               \
                                    + (size_t)lane*16u,                      \
                                &lds[(ibk & 1) ^ 1][(wv*6 + k)*1024          \
                                                    + lane*16]);             \
            }                                                                \
            /* B prefetch dist 2 into slot (p+2)%3 */                        \
            if (p < 16) {                                                    \
                const int np = p + 2;                                        \
                uint32_t a0 = baddr[np>>1][0] ^ (uint32_t)((np&1)*32);       \
                uint32_t a1 = baddr[np>>1][1] ^ (uint32_t)((np&1)*32);       \
                Bb[(p+2)%3][0] = *(const bf16x8*)(lds0 + a0);                \
                Bb[(p+2)%3][1] = *(const bf16x8*)(lds0 + a1);                \
            }                                                                \
            __builtin_amdgcn_s_setprio(1);                                   \
            acc[0][0] = __builtin_amdgcn_mfma_f32_32x32x16_bf16(A[p%3][0], Bb[p%3][0], acc[0][0], 0, 0, 0); \
            acc[0][1] = __builtin_amdgcn_mfma_f32_32x32x16_bf16(A[p%3][1], Bb[p%3][0], acc[0][1], 0, 0, 0); \
            acc[1][0] = __builtin_amdgcn_mfma_f32_32x32x16_bf16(A[p%3][0], Bb[p%3][1], acc[1][0], 0, 0, 0); \
            acc[1][1] = __builtin_amdgcn_mfma_f32_32x32x16_bf16(A[p%3][1], Bb[p%3][1], acc[1][1], 0, 0, 0); \
            __builtin_amdgcn_s_setprio(0);                                   \
        }                                                                    \
    }

    int flipd = 24576;   // +/-24576 alternating buffer-flip (ADD, not XOR)
    for (int ibk = 0; ibk < 15; ++ibk) {
        IBK_PHASES(0)
        // flip B addresses to the other buffer; advance A base
#pragma unroll
        for (int pos = 0; pos < 9; ++pos) {
            baddr[pos][0] += (uint32_t)flipd;
            baddr[pos][1] += (uint32_t)flipd;
        }
        flipd = -flipd;
        abase += 18432;
        // Counted barrier (T4): 4 newest vmem ops (p16/p17 cross-ibk A
        // prefetches) stay in flight; DMA + older A loads must complete.
        asm volatile("s_waitcnt vmcnt(4) lgkmcnt(0)" ::: "memory");
        __builtin_amdgcn_s_barrier();
        __builtin_amdgcn_sched_barrier(0);
    }
    {
        const int ibk = 15;
        (void)ibk;
        IBK_PHASES(1)
    }
#undef IBK_PHASES

    // fused LSTM epilogue. col = l31 (m), r = 4*q + gate,
    // ch = cb*32 + fg*8 + 2*q + hl.
    float* outh = out;
    float* outc = out + (size_t)OUT_HALF;
    const size_t bOff = (size_t)b * (256*256);
#pragma unroll
    for (int mf = 0; mf < 2; ++mf) {
        int m = wv*64 + mf*32 + l31;
#pragma unroll
        for (int f = 0; f < 2; ++f) {
            int fg = nh*2 + f;
#pragma unroll
            for (int q = 0; q < 4; ++q) {
                int ch = cb*32 + fg*8 + 2*q + hl;
                size_t pidx = (size_t)ch*256 + (size_t)m;
                size_t idx  = bOff + pidx;
                float cv = cin[idx];
                float pi = acc[mf][f][4*q+0];
                float pf = acc[mf][f][4*q+1];
                float pc = acc[mf][f][4*q+2];
                float po = acc[mf][f][4*q+3];
                float it = 1.f/(1.f + __expf(-(pi + Wci[pidx]*cv)));
                float ft = 1.f/(1.f + __expf(-(pf + Wcf[pidx]*cv)));
                float tc = 1.f - 2.f/(1.f + __expf(2.f*pc));
                float ct = ft*cv + it*tc;
                float ot = 1.f/(1.f + __expf(-(po + Wco[pidx]*ct)));
                float th = 1.f - 2.f/(1.f + __expf(2.f*ct));
                outh[idx] = ot*th;
                outc[idx] = ct;
            }
        }
    }
}

// ---------------------------------------------------------------------------
extern "C" void kernel_launch(void* const* d_in, const int* in_sizes, int n_in,
                              void* d_out, int out_size, void* d_ws, size_t ws_size,
                              hipStream_t stream)
{
    const float* x   = (const float*)d_in[0];
    const float* h   = (const float*)d_in[1];
    const float* c   = (const float*)d_in[2];
    const float* Wx  = (const float*)d_in[3];
    const float* Wh  = (const float*)d_in[4];
    const float* bh  = (const float*)d_in[5];
    const float* Wci = (const float*)d_in[6];
    const float* Wcf = (const float*)d_in[7];
    const float* Wco = (const float*)d_in[8];
    float* out = (float*)d_out;

    unsigned char* xh = (unsigned char*)d_ws;        // padded plane store
    __bf16* Wt = (__bf16*)(xh + (size_t)XH_BYTES + 4096); // +slack

    hipLaunchKernelGGL(xh_transform, dim3(4096), dim3(256), 0, stream, x, h, xh);
    hipLaunchKernelGGL(w_transform,  dim3(2304), dim3(256), 0, stream, Wx, Wh, Wt);
    hipLaunchKernelGGL(convlstm_main, dim3(4096), dim3(256), 0, stream,
                       xh, Wt, bh, c, Wci, Wcf, Wco, out);
}

// Round 18
// 587.992 us; speedup vs baseline: 1.5099x; 1.0762x over previous
//
#include <hip/hip_runtime.h>

// ConvLSTM cell, MI355X. Implicit-GEMM over concat(x,h) channels, bf16 MFMA
// 32x32x16, fused in-register LSTM epilogue.
// R18: L1-pressure fix. Wave tile 128m x 64oc (acc[4][2] = 128 AGPR):
// A loads per phase unchanged (2) but amortized over 8 MFMA -> per-CU L1
// demand halves (62->31 B/cyc). Block = (b, cb), 4 waves = 2 wm x 2 wf,
// grid 2048. B addresses: addr(mf+1) = (addr+2304)^64, addr(mf+2) = +4608
// (carry-safe). A dist-1 ping (literal offsets), B dist-1 ping, DMA at p1,
// counted vmcnt(2) barrier, last ibk peeled.

typedef __bf16 bf16x8 __attribute__((ext_vector_type(8)));
typedef float f32x16 __attribute__((ext_vector_type(16)));

#define PLANE_B  20736u                 // 324 positions * 64 B (18x18x32 bf16)
#define XH_BYTES (4096u * PLANE_B)      // 256 b * 16 icblk planes
#define OUT_HALF 16777216u              // B*CH*S

__device__ inline void gload_lds16(const void* g, void* l) {
    __builtin_amdgcn_global_load_lds(
        (const __attribute__((address_space(1))) void*)g,
        (__attribute__((address_space(3))) void*)l, 16, 0, 0);
}

// ---------------------------------------------------------------------------
// P1a: x,h (NCHW fp32) -> padded swizzled bf16 planes (unchanged from R13).
// addr = (p*64 + ofs) ^ ((p&7)<<4)  (bijective; same formula on read).
__global__ __launch_bounds__(256) void xh_transform(
    const float* __restrict__ x, const float* __restrict__ hh,
    unsigned char* __restrict__ xh)
{
    int blk = blockIdx.x;              // b*16 + ibk
    int b = blk >> 4, ibk = blk & 15;
    const float* src = (ibk < 8) ? (x  + ((size_t)(b*256 + ibk*32)) * 256)
                                 : (hh + ((size_t)(b*256 + (ibk-8)*32)) * 256);
    int t = threadIdx.x;               // t == spatial s
    uint32_t w[16];
#pragma unroll
    for (int i = 0; i < 16; ++i) {
        __bf16 lo = (__bf16)src[(size_t)(2*i  )*256 + t];
        __bf16 hi = (__bf16)src[(size_t)(2*i+1)*256 + t];
        w[i] = (uint32_t)__builtin_bit_cast(unsigned short, lo)
             | ((uint32_t)__builtin_bit_cast(unsigned short, hi) << 16);
    }
    unsigned char* plane = xh + (size_t)blk * PLANE_B;
    int p = ((t >> 4) + 1)*18 + (t & 15) + 1;      // interior position
    uint32_t key  = (uint32_t)(p & 7) << 4;
    uint32_t base = (uint32_t)p * 64u;
#pragma unroll
    for (int k = 0; k < 4; ++k)
        *(uint4*)(plane + ((base + 16u*k) ^ key)) =
            uint4{w[4*k], w[4*k+1], w[4*k+2], w[4*k+3]};
    // zero the 68 border positions (rows 0,17; cols 0,17)
    if (t < 68) {
        int pb;
        if      (t < 18) pb = t;                   // row 0
        else if (t < 36) pb = 17*18 + (t - 18);    // row 17
        else if (t < 52) pb = (t - 35)*18;         // rows 1..16, col 0
        else             pb = (t - 51)*18 + 17;    // rows 1..16, col 17
        uint32_t kb = (uint32_t)(pb & 7) << 4;
        uint32_t bb = (uint32_t)pb * 64u;
        uint4 z{0u,0u,0u,0u};
#pragma unroll
        for (int k = 0; k < 4; ++k)
            *(uint4*)(plane + ((bb + 16u*k) ^ kb)) = z;
    }
}

// ---------------------------------------------------------------------------
// P1b: Wx,Wh (OIHW fp32) -> Wt bf16 in A-fragment order.
// chunk = ((cb*16 + ibk)*9 + pos)*8 + half*4 + f ; 64 lanes x 8 bf16 each.
// Byte layout: cb*1179648 + ibk*73728 + pos*8192 + half*4096 + f*1024.
__global__ __launch_bounds__(256) void w_transform(
    const float* __restrict__ Wx, const float* __restrict__ Wh,
    __bf16* __restrict__ Wt)
{
    int idx  = blockIdx.x * 256 + threadIdx.x;   // 589824 total
    int lane = idx & 63;
    int chunk = idx >> 6;                        // 9216 chunks
    int f    = chunk & 3;
    int half = (chunk >> 2) & 1;
    int pos  = (chunk >> 3) % 9;                 // ky*3+kx
    int rest = (chunk >> 3) / 9;                 // 0..127
    int ibk  = rest & 15;
    int cb   = rest >> 4;                        // 0..7
    int row = lane & 31, hl = lane >> 5;
    int gate = row & 3, ch8 = row >> 2;
    int oc  = gate*256 + cb*32 + f*8 + ch8;
    int ic0 = ibk*32 + half*16 + hl*8;
    bf16x8 v;
#pragma unroll
    for (int j = 0; j < 8; ++j) {
        int ic = ic0 + j;
        float w = (ic < 256) ? Wx[((size_t)oc*256 + ic      )*9 + pos]
                             : Wh[((size_t)oc*256 + (ic-256))*9 + pos];
        v[j] = (__bf16)w;
    }
    *(bf16x8*)(Wt + (size_t)chunk*512 + (size_t)lane*8) = v;
}

// ---------------------------------------------------------------------------
// Main. Block = (b, cb): 256m x 128oc'. 4 waves = (wm, wf), each 128m x 64oc:
// acc[4][2] f32x16 = 128 AGPR. 18 phases/ibk; A dist-1 ping (2 frags), B
// dist-1 ping (4 m-frags), DMA at phase 1, counted vmcnt(2) barrier.
__global__ __launch_bounds__(256, 2) void convlstm_main(
    const unsigned char* __restrict__ xh, const unsigned char* __restrict__ Wtb,
    const float* __restrict__ bh,  const float* __restrict__ cin,
    const float* __restrict__ Wci, const float* __restrict__ Wcf,
    const float* __restrict__ Wco, float* __restrict__ out)
{
    int bid = blockIdx.x;               // b*8 + cb
    int cb  = bid & 7;
    int b   = bid >> 3;
    int tid = threadIdx.x;
    int lane = tid & 63, wv = tid >> 6;
    int wm = wv & 1, wf = wv >> 1;
    int l31 = lane & 31, hl = lane >> 5;

    __shared__ __align__(16) unsigned char lds[2][24576];

    // accumulators init with bias bh[oc]; wave's f-pair = wf*2 + j
    f32x16 acc[4][2];
#pragma unroll
    for (int j = 0; j < 2; ++j) {
        int fg = wf*2 + j;
        f32x16 v;
#pragma unroll
        for (int r = 0; r < 16; ++r) {
            int gate = r & 3, q = r >> 2;
            v[r] = bh[gate*256 + cb*32 + fg*8 + 2*q + hl];
        }
        acc[0][j] = v; acc[1][j] = v; acc[2][j] = v; acc[3][j] = v;
    }

    const unsigned char* planes = xh + (size_t)b * (16u * PLANE_B);

    // stage plane 0 into buffer 0 (linear DMA; plane pre-padded+swizzled)
#pragma unroll
    for (int k = 0; k < 6; ++k)
        gload_lds16(planes + (size_t)(wv*6 + k)*1024u + (size_t)lane*16u,
                    &lds[0][(wv*6 + k)*1024 + lane*16]);

    // B LDS addresses for mf=0 and mf=1; mf=2/3 are +4608 literal.
    // m(mf) = wm*128 + mf*32 + l31 -> p(mf) = p(0) + 36*mf.
    // addr(mf=1) = (addr(mf=0) + 2304) ^ 64  [carry-safe: 2304 = 0x900]
    int m0 = wm*128 + l31;
    int pb0 = (m0 >> 4)*18 + (m0 & 15);
    const uint32_t kbase = (uint32_t)(hl*16);
    uint32_t baddr[9][2];
#pragma unroll
    for (int pos = 0; pos < 9; ++pos) {
        int d = (pos/3)*18 + (pos%3);
        int pp = pb0 + d;
        uint32_t a = ((uint32_t)pp*64u + kbase) ^ (((uint32_t)(pp & 7)) << 4);
        baddr[pos][0] = a;
        baddr[pos][1] = (a + 2304u) ^ 64u;
    }
    const char* lds0 = (const char*)&lds[0][0];

    // A pointer: uniform base + wf f-pair + lane; phase offsets literal.
    const unsigned char* aptr = Wtb + (size_t)cb*1179648u
                                    + (size_t)(wf*2048) + (size_t)(lane*16);

    bf16x8 A[2][2], Bb[2][4];
    // A prologue: (ibk0, ph0) into A[0]
    A[0][0] = *(const bf16x8*)(aptr + 0);
    A[0][1] = *(const bf16x8*)(aptr + 1024);

    __syncthreads();   // initial DMA drained (full), waves joined

// One ibk body. LAST literal gates DMA + clamps the p17 cross-ibk prefetch.
#define IBK_PHASES(LAST)                                                     \
    {                                                                        \
        /* B prologue: pos0/half0, 4 m-frags (data valid after barrier) */   \
        Bb[0][0] = *(const bf16x8*)(lds0 + baddr[0][0]);                     \
        Bb[0][1] = *(const bf16x8*)(lds0 + baddr[0][1]);                     \
        Bb[0][2] = *(const bf16x8*)(lds0 + baddr[0][0] + 4608);              \
        Bb[0][3] = *(const bf16x8*)(lds0 + baddr[0][1] + 4608);              \
        _Pragma("unroll")                                                    \
        for (int p = 0; p < 18; ++p) {                                       \
            /* A prefetch dist-1: phase p+1 (p17 -> next ibk ph0 at 73728;   \
               LAST clamps to a dummy in-slice reload) */                    \
            {                                                                \
                const int noff = ((LAST) && p == 17) ? (17*4096)             \
                                                     : ((p+1)*4096);         \
                A[(p+1)&1][0] = *(const bf16x8*)(aptr + noff);               \
                A[(p+1)&1][1] = *(const bf16x8*)(aptr + noff + 1024);        \
            }                                                                \
            if (p == 1 && !(LAST)) {                                         \
                const unsigned char* np_ = planes + (size_t)(ibk+1)*PLANE_B; \
                _Pragma("unroll")                                            \
                for (int k = 0; k < 6; ++k)                                  \
                    gload_lds16(np_ + (size_t)(wv*6 + k)*1024u               \
                                    + (size_t)lane*16u,                      \
                                &lds[(ibk & 1) ^ 1][(wv*6 + k)*1024          \
                                                    + lane*16]);             \
            }                                                                \
            /* B prefetch dist-1: phase p+1, 4 m-frags */                    \
            if (p < 17) {                                                    \
                const int np = p + 1;                                        \
                const uint32_t hx = (uint32_t)((np & 1)*32);                 \
                uint32_t a0 = baddr[np>>1][0] ^ hx;                          \
                uint32_t a1 = baddr[np>>1][1] ^ hx;                          \
                Bb[np&1][0] = *(const bf16x8*)(lds0 + a0);                   \
                Bb[np&1][1] = *(const bf16x8*)(lds0 + a1);                   \
                Bb[np&1][2] = *(const bf16x8*)(lds0 + a0 + 4608);            \
                Bb[np&1][3] = *(const bf16x8*)(lds0 + a1 + 4608);            \
            }                                                                \
            __builtin_amdgcn_s_setprio(1);                                   \
            acc[0][0] = __builtin_amdgcn_mfma_f32_32x32x16_bf16(A[p&1][0], Bb[p&1][0], acc[0][0], 0, 0, 0); \
            acc[0][1] = __builtin_amdgcn_mfma_f32_32x32x16_bf16(A[p&1][1], Bb[p&1][0], acc[0][1], 0, 0, 0); \
            acc[1][0] = __builtin_amdgcn_mfma_f32_32x32x16_bf16(A[p&1][0], Bb[p&1][1], acc[1][0], 0, 0, 0); \
            acc[1][1] = __builtin_amdgcn_mfma_f32_32x32x16_bf16(A[p&1][1], Bb[p&1][1], acc[1][1], 0, 0, 0); \
            acc[2][0] = __builtin_amdgcn_mfma_f32_32x32x16_bf16(A[p&1][0], Bb[p&1][2], acc[2][0], 0, 0, 0); \
            acc[2][1] = __builtin_amdgcn_mfma_f32_32x32x16_bf16(A[p&1][1], Bb[p&1][2], acc[2][1], 0, 0, 0); \
            acc[3][0] = __builtin_amdgcn_mfma_f32_32x32x16_bf16(A[p&1][0], Bb[p&1][3], acc[3][0], 0, 0, 0); \
            acc[3][1] = __builtin_amdgcn_mfma_f32_32x32x16_bf16(A[p&1][1], Bb[p&1][3], acc[3][1], 0, 0, 0); \
            __builtin_amdgcn_s_setprio(0);                                   \
        }                                                                    \
    }

    int flipd = 24576;   // +/-24576 alternating buffer-flip (ADD, not XOR)
    for (int ibk = 0; ibk < 15; ++ibk) {
        IBK_PHASES(0)
        // flip B addresses to the other buffer; advance A base
#pragma unroll
        for (int pos = 0; pos < 9; ++pos) {
            baddr[pos][0] += (uint32_t)flipd;
            baddr[pos][1] += (uint32_t)flipd;
        }
        flipd = -flipd;
        aptr += 73728;
        // Counted barrier (T4): only p17's 2 A prefetches stay in flight;
        // DMA + all older A loads must be complete.
        asm volatile("s_waitcnt vmcnt(2) lgkmcnt(0)" ::: "memory");
        __builtin_amdgcn_s_barrier();
        __builtin_amdgcn_sched_barrier(0);
    }
    {
        const int ibk = 15;
        (void)ibk;
        IBK_PHASES(1)
    }
#undef IBK_PHASES

    // fused LSTM epilogue. col = l31 (m), r = 4*q + gate,
    // ch = cb*32 + (wf*2+j)*8 + 2*q + hl ; m = wm*128 + mf*32 + l31.
    float* outh = out;
    float* outc = out + (size_t)OUT_HALF;
    const size_t bOff = (size_t)b * (256*256);
#pragma unroll
    for (int mf = 0; mf < 4; ++mf) {
        int m = wm*128 + mf*32 + l31;
#pragma unroll
        for (int j = 0; j < 2; ++j) {
            int fg = wf*2 + j;
#pragma unroll
            for (int q = 0; q < 4; ++q) {
                int ch = cb*32 + fg*8 + 2*q + hl;
                size_t pidx = (size_t)ch*256 + (size_t)m;
                size_t idx  = bOff + pidx;
                float cv = cin[idx];
                float pi = acc[mf][j][4*q+0];
                float pf = acc[mf][j][4*q+1];
                float pc = acc[mf][j][4*q+2];
                float po = acc[mf][j][4*q+3];
                float it = 1.f/(1.f + __expf(-(pi + Wci[pidx]*cv)));
                float ft = 1.f/(1.f + __expf(-(pf + Wcf[pidx]*cv)));
                float tc = 1.f - 2.f/(1.f + __expf(2.f*pc));
                float ct = ft*cv + it*tc;
                float ot = 1.f/(1.f + __expf(-(po + Wco[pidx]*ct)));
                float th = 1.f - 2.f/(1.f + __expf(2.f*ct));
                outh[idx] = ot*th;
                outc[idx] = ct;
            }
        }
    }
}

// ---------------------------------------------------------------------------
extern "C" void kernel_launch(void* const* d_in, const int* in_sizes, int n_in,
                              void* d_out, int out_size, void* d_ws, size_t ws_size,
                              hipStream_t stream)
{
    const float* x   = (const float*)d_in[0];
    const float* h   = (const float*)d_in[1];
    const float* c   = (const float*)d_in[2];
    const float* Wx  = (const float*)d_in[3];
    const float* Wh  = (const float*)d_in[4];
    const float* bh  = (const float*)d_in[5];
    const float* Wci = (const float*)d_in[6];
    const float* Wcf = (const float*)d_in[7];
    const float* Wco = (const float*)d_in[8];
    float* out = (float*)d_out;

    unsigned char* xh = (unsigned char*)d_ws;        // padded plane store
    unsigned char* wtb = xh + (size_t)XH_BYTES + 4096; // weights after slack

    hipLaunchKernelGGL(xh_transform, dim3(4096), dim3(256), 0, stream, x, h, xh);
    hipLaunchKernelGGL(w_transform,  dim3(2304), dim3(256), 0, stream,
                       Wx, Wh, (__bf16*)wtb);
    hipLaunchKernelGGL(convlstm_main, dim3(2048), dim3(256), 0, stream,
                       xh, wtb, bh, c, Wci, Wcf, Wco, out);
}

// Round 19
// 580.867 us; speedup vs baseline: 1.5284x; 1.0123x over previous
//
#include <hip/hip_runtime.h>

// ConvLSTM cell, MI355X. Implicit-GEMM over concat(x,h) channels, bf16 MFMA
// 32x32x16, fused in-register LSTM epilogue.
// R19: R18 (128m x 64oc waves, acc[4][2]=128 AGPR, grid 2048) + A dist-2
// restored (3-slot %3 rotation; cover 512+ cyc for the L1-missing A loads).
// Counted barrier vmcnt(4). Register budget: ~124 arch + 128 AGPR = 252/256.

typedef __bf16 bf16x8 __attribute__((ext_vector_type(8)));
typedef float f32x16 __attribute__((ext_vector_type(16)));

#define PLANE_B  20736u                 // 324 positions * 64 B (18x18x32 bf16)
#define XH_BYTES (4096u * PLANE_B)      // 256 b * 16 icblk planes
#define OUT_HALF 16777216u              // B*CH*S

__device__ inline void gload_lds16(const void* g, void* l) {
    __builtin_amdgcn_global_load_lds(
        (const __attribute__((address_space(1))) void*)g,
        (__attribute__((address_space(3))) void*)l, 16, 0, 0);
}

// ---------------------------------------------------------------------------
// P1a: x,h (NCHW fp32) -> padded swizzled bf16 planes.
// addr = (p*64 + ofs) ^ ((p&7)<<4)  (bijective; same formula on read).
__global__ __launch_bounds__(256) void xh_transform(
    const float* __restrict__ x, const float* __restrict__ hh,
    unsigned char* __restrict__ xh)
{
    int blk = blockIdx.x;              // b*16 + ibk
    int b = blk >> 4, ibk = blk & 15;
    const float* src = (ibk < 8) ? (x  + ((size_t)(b*256 + ibk*32)) * 256)
                                 : (hh + ((size_t)(b*256 + (ibk-8)*32)) * 256);
    int t = threadIdx.x;               // t == spatial s
    uint32_t w[16];
#pragma unroll
    for (int i = 0; i < 16; ++i) {
        __bf16 lo = (__bf16)src[(size_t)(2*i  )*256 + t];
        __bf16 hi = (__bf16)src[(size_t)(2*i+1)*256 + t];
        w[i] = (uint32_t)__builtin_bit_cast(unsigned short, lo)
             | ((uint32_t)__builtin_bit_cast(unsigned short, hi) << 16);
    }
    unsigned char* plane = xh + (size_t)blk * PLANE_B;
    int p = ((t >> 4) + 1)*18 + (t & 15) + 1;      // interior position
    uint32_t key  = (uint32_t)(p & 7) << 4;
    uint32_t base = (uint32_t)p * 64u;
#pragma unroll
    for (int k = 0; k < 4; ++k)
        *(uint4*)(plane + ((base + 16u*k) ^ key)) =
            uint4{w[4*k], w[4*k+1], w[4*k+2], w[4*k+3]};
    // zero the 68 border positions (rows 0,17; cols 0,17)
    if (t < 68) {
        int pb;
        if      (t < 18) pb = t;                   // row 0
        else if (t < 36) pb = 17*18 + (t - 18);    // row 17
        else if (t < 52) pb = (t - 35)*18;         // rows 1..16, col 0
        else             pb = (t - 51)*18 + 17;    // rows 1..16, col 17
        uint32_t kb = (uint32_t)(pb & 7) << 4;
        uint32_t bb = (uint32_t)pb * 64u;
        uint4 z{0u,0u,0u,0u};
#pragma unroll
        for (int k = 0; k < 4; ++k)
            *(uint4*)(plane + ((bb + 16u*k) ^ kb)) = z;
    }
}

// ---------------------------------------------------------------------------
// P1b: Wx,Wh (OIHW fp32) -> Wt bf16 in A-fragment order.
// chunk = ((cb*16 + ibk)*9 + pos)*8 + half*4 + f ; 64 lanes x 8 bf16 each.
// Byte layout: cb*1179648 + ibk*73728 + pos*8192 + half*4096 + f*1024.
__global__ __launch_bounds__(256) void w_transform(
    const float* __restrict__ Wx, const float* __restrict__ Wh,
    __bf16* __restrict__ Wt)
{
    int idx  = blockIdx.x * 256 + threadIdx.x;   // 589824 total
    int lane = idx & 63;
    int chunk = idx >> 6;                        // 9216 chunks
    int f    = chunk & 3;
    int half = (chunk >> 2) & 1;
    int pos  = (chunk >> 3) % 9;                 // ky*3+kx
    int rest = (chunk >> 3) / 9;                 // 0..127
    int ibk  = rest & 15;
    int cb   = rest >> 4;                        // 0..7
    int row = lane & 31, hl = lane >> 5;
    int gate = row & 3, ch8 = row >> 2;
    int oc  = gate*256 + cb*32 + f*8 + ch8;
    int ic0 = ibk*32 + half*16 + hl*8;
    bf16x8 v;
#pragma unroll
    for (int j = 0; j < 8; ++j) {
        int ic = ic0 + j;
        float w = (ic < 256) ? Wx[((size_t)oc*256 + ic      )*9 + pos]
                             : Wh[((size_t)oc*256 + (ic-256))*9 + pos];
        v[j] = (__bf16)w;
    }
    *(bf16x8*)(Wt + (size_t)chunk*512 + (size_t)lane*8) = v;
}

// ---------------------------------------------------------------------------
// Main. Block = (b, cb): 256m x 128oc'. 4 waves = (wm, wf), each 128m x 64oc:
// acc[4][2] f32x16 = 128 AGPR. 18 phases/ibk; A dist-2 (%3 slots), B dist-1
// ping (4 m-frags), DMA at phase 1, counted vmcnt(4) barrier.
__global__ __launch_bounds__(256, 2) void convlstm_main(
    const unsigned char* __restrict__ xh, const unsigned char* __restrict__ Wtb,
    const float* __restrict__ bh,  const float* __restrict__ cin,
    const float* __restrict__ Wci, const float* __restrict__ Wcf,
    const float* __restrict__ Wco, float* __restrict__ out)
{
    int bid = blockIdx.x;               // b*8 + cb
    int cb  = bid & 7;
    int b   = bid >> 3;
    int tid = threadIdx.x;
    int lane = tid & 63, wv = tid >> 6;
    int wm = wv & 1, wf = wv >> 1;
    int l31 = lane & 31, hl = lane >> 5;

    __shared__ __align__(16) unsigned char lds[2][24576];

    // accumulators init with bias bh[oc]; wave's f-pair = wf*2 + j
    f32x16 acc[4][2];
#pragma unroll
    for (int j = 0; j < 2; ++j) {
        int fg = wf*2 + j;
        f32x16 v;
#pragma unroll
        for (int r = 0; r < 16; ++r) {
            int gate = r & 3, q = r >> 2;
            v[r] = bh[gate*256 + cb*32 + fg*8 + 2*q + hl];
        }
        acc[0][j] = v; acc[1][j] = v; acc[2][j] = v; acc[3][j] = v;
    }

    const unsigned char* planes = xh + (size_t)b * (16u * PLANE_B);

    // stage plane 0 into buffer 0 (linear DMA; plane pre-padded+swizzled)
#pragma unroll
    for (int k = 0; k < 6; ++k)
        gload_lds16(planes + (size_t)(wv*6 + k)*1024u + (size_t)lane*16u,
                    &lds[0][(wv*6 + k)*1024 + lane*16]);

    // B LDS addresses for mf=0 and mf=1; mf=2/3 are +4608 literal.
    // m(mf) = wm*128 + mf*32 + l31 -> p(mf) = p(0) + 36*mf.
    // addr(mf=1) = (addr(mf=0) + 2304) ^ 64  [carry-safe: 2304 = 0x900]
    int m0 = wm*128 + l31;
    int pb0 = (m0 >> 4)*18 + (m0 & 15);
    const uint32_t kbase = (uint32_t)(hl*16);
    uint32_t baddr[9][2];
#pragma unroll
    for (int pos = 0; pos < 9; ++pos) {
        int d = (pos/3)*18 + (pos%3);
        int pp = pb0 + d;
        uint32_t a = ((uint32_t)pp*64u + kbase) ^ (((uint32_t)(pp & 7)) << 4);
        baddr[pos][0] = a;
        baddr[pos][1] = (a + 2304u) ^ 64u;
    }
    const char* lds0 = (const char*)&lds[0][0];

    // A pointer: uniform base + wf f-pair + lane; phase offsets literal.
    const unsigned char* aptr = Wtb + (size_t)cb*1179648u
                                    + (size_t)(wf*2048) + (size_t)(lane*16);

    bf16x8 A[3][2], Bb[2][4];
    // A prologue: (ibk0, ph0) -> slot 0, (ibk0, ph1) -> slot 1
    A[0][0] = *(const bf16x8*)(aptr + 0);
    A[0][1] = *(const bf16x8*)(aptr + 1024);
    A[1][0] = *(const bf16x8*)(aptr + 4096);
    A[1][1] = *(const bf16x8*)(aptr + 5120);

    __syncthreads();   // initial DMA drained (full), waves joined

// One ibk body. LAST literal gates DMA + clamps the cross-ibk A prefetch.
// A dist-2: prefetch phase p+2 into slot (p+2)%3 (18%3==0 -> static slots;
// p=16,17 cross into next ibk at +73728).
#define IBK_PHASES(LAST)                                                     \
    {                                                                        \
        /* B prologue: pos0/half0, 4 m-frags (data valid after barrier) */   \
        Bb[0][0] = *(const bf16x8*)(lds0 + baddr[0][0]);                     \
        Bb[0][1] = *(const bf16x8*)(lds0 + baddr[0][1]);                     \
        Bb[0][2] = *(const bf16x8*)(lds0 + baddr[0][0] + 4608);              \
        Bb[0][3] = *(const bf16x8*)(lds0 + baddr[0][1] + 4608);              \
        _Pragma("unroll")                                                    \
        for (int p = 0; p < 18; ++p) {                                       \
            /* A prefetch dist-2 into slot (p+2)%3 */                        \
            {                                                                \
                const int tp = p + 2;                                        \
                const int off = (tp < 18)                                    \
                    ? (tp*4096)                                              \
                    : ((LAST) ? (17*4096)                 /* dummy */        \
                              : (73728 + (tp-18)*4096));                     \
                A[(p+2)%3][0] = *(const bf16x8*)(aptr + off);                \
                A[(p+2)%3][1] = *(const bf16x8*)(aptr + off + 1024);         \
            }                                                                \
            if (p == 1 && !(LAST)) {                                         \
                const unsigned char* np_ = planes + (size_t)(ibk+1)*PLANE_B; \
                _Pragma("unroll")                                            \
                for (int k = 0; k < 6; ++k)                                  \
                    gload_lds16(np_ + (size_t)(wv*6 + k)*1024u               \
                                    + (size_t)lane*16u,                      \
                                &lds[(ibk & 1) ^ 1][(wv*6 + k)*1024          \
                                                    + lane*16]);             \
            }                                                                \
            /* B prefetch dist-1: phase p+1, 4 m-frags */                    \
            if (p < 17) {                                                    \
                const int np = p + 1;                                        \
                const uint32_t hx = (uint32_t)((np & 1)*32);                 \
                uint32_t a0 = baddr[np>>1][0] ^ hx;                          \
                uint32_t a1 = baddr[np>>1][1] ^ hx;                          \
                Bb[np&1][0] = *(const bf16x8*)(lds0 + a0);                   \
                Bb[np&1][1] = *(const bf16x8*)(lds0 + a1);                   \
                Bb[np&1][2] = *(const bf16x8*)(lds0 + a0 + 4608);            \
                Bb[np&1][3] = *(const bf16x8*)(lds0 + a1 + 4608);            \
            }                                                                \
            __builtin_amdgcn_s_setprio(1);                                   \
            acc[0][0] = __builtin_amdgcn_mfma_f32_32x32x16_bf16(A[p%3][0], Bb[p&1][0], acc[0][0], 0, 0, 0); \
            acc[0][1] = __builtin_amdgcn_mfma_f32_32x32x16_bf16(A[p%3][1], Bb[p&1][0], acc[0][1], 0, 0, 0); \
            acc[1][0] = __builtin_amdgcn_mfma_f32_32x32x16_bf16(A[p%3][0], Bb[p&1][1], acc[1][0], 0, 0, 0); \
            acc[1][1] = __builtin_amdgcn_mfma_f32_32x32x16_bf16(A[p%3][1], Bb[p&1][1], acc[1][1], 0, 0, 0); \
            acc[2][0] = __builtin_amdgcn_mfma_f32_32x32x16_bf16(A[p%3][0], Bb[p&1][2], acc[2][0], 0, 0, 0); \
            acc[2][1] = __builtin_amdgcn_mfma_f32_32x32x16_bf16(A[p%3][1], Bb[p&1][2], acc[2][1], 0, 0, 0); \
            acc[3][0] = __builtin_amdgcn_mfma_f32_32x32x16_bf16(A[p%3][0], Bb[p&1][3], acc[3][0], 0, 0, 0); \
            acc[3][1] = __builtin_amdgcn_mfma_f32_32x32x16_bf16(A[p%3][1], Bb[p&1][3], acc[3][1], 0, 0, 0); \
            __builtin_amdgcn_s_setprio(0);                                   \
        }                                                                    \
    }

    int flipd = 24576;   // +/-24576 alternating buffer-flip (ADD, not XOR)
    for (int ibk = 0; ibk < 15; ++ibk) {
        IBK_PHASES(0)
        // flip B addresses to the other buffer; advance A base
#pragma unroll
        for (int pos = 0; pos < 9; ++pos) {
            baddr[pos][0] += (uint32_t)flipd;
            baddr[pos][1] += (uint32_t)flipd;
        }
        flipd = -flipd;
        aptr += 73728;
        // Counted barrier (T4): p16/p17's 4 cross-ibk A prefetches stay in
        // flight; DMA + all older A loads must be complete.
        asm volatile("s_waitcnt vmcnt(4) lgkmcnt(0)" ::: "memory");
        __builtin_amdgcn_s_barrier();
        __builtin_amdgcn_sched_barrier(0);
    }
    {
        const int ibk = 15;
        (void)ibk;
        IBK_PHASES(1)
    }
#undef IBK_PHASES

    // fused LSTM epilogue. col = l31 (m), r = 4*q + gate,
    // ch = cb*32 + (wf*2+j)*8 + 2*q + hl ; m = wm*128 + mf*32 + l31.
    float* outh = out;
    float* outc = out + (size_t)OUT_HALF;
    const size_t bOff = (size_t)b * (256*256);
#pragma unroll
    for (int mf = 0; mf < 4; ++mf) {
        int m = wm*128 + mf*32 + l31;
#pragma unroll
        for (int j = 0; j < 2; ++j) {
            int fg = wf*2 + j;
#pragma unroll
            for (int q = 0; q < 4; ++q) {
                int ch = cb*32 + fg*8 + 2*q + hl;
                size_t pidx = (size_t)ch*256 + (size_t)m;
                size_t idx  = bOff + pidx;
                float cv = cin[idx];
                float pi = acc[mf][j][4*q+0];
                float pf = acc[mf][j][4*q+1];
                float pc = acc[mf][j][4*q+2];
                float po = acc[mf][j][4*q+3];
                float it = 1.f/(1.f + __expf(-(pi + Wci[pidx]*cv)));
                float ft = 1.f/(1.f + __expf(-(pf + Wcf[pidx]*cv)));
                float tc = 1.f - 2.f/(1.f + __expf(2.f*pc));
                float ct = ft*cv + it*tc;
                float ot = 1.f/(1.f + __expf(-(po + Wco[pidx]*ct)));
                float th = 1.f - 2.f/(1.f + __expf(2.f*ct));
                outh[idx] = ot*th;
                outc[idx] = ct;
            }
        }
    }
}

// ---------------------------------------------------------------------------
extern "C" void kernel_launch(void* const* d_in, const int* in_sizes, int n_in,
                              void* d_out, int out_size, void* d_ws, size_t ws_size,
                              hipStream_t stream)
{
    const float* x   = (const float*)d_in[0];
    const float* h   = (const float*)d_in[1];
    const float* c   = (const float*)d_in[2];
    const float* Wx  = (const float*)d_in[3];
    const float* Wh  = (const float*)d_in[4];
    const float* bh  = (const float*)d_in[5];
    const float* Wci = (const float*)d_in[6];
    const float* Wcf = (const float*)d_in[7];
    const float* Wco = (const float*)d_in[8];
    float* out = (float*)d_out;

    unsigned char* xh = (unsigned char*)d_ws;        // padded plane store
    unsigned char* wtb = xh + (size_t)XH_BYTES + 4096; // weights after slack

    hipLaunchKernelGGL(xh_transform, dim3(4096), dim3(256), 0, stream, x, h, xh);
    hipLaunchKernelGGL(w_transform,  dim3(2304), dim3(256), 0, stream,
                       Wx, Wh, (__bf16*)wtb);
    hipLaunchKernelGGL(convlstm_main, dim3(2048), dim3(256), 0, stream,
                       xh, wtb, bh, c, Wci, Wcf, Wco, out);
}

// Round 20
// 579.476 us; speedup vs baseline: 1.5321x; 1.0024x over previous
//
#include <hip/hip_runtime.h>

// ConvLSTM cell, MI355X. Implicit-GEMM over concat(x,h) channels, bf16 MFMA
// 32x32x16, fused in-register LSTM epilogue.
// R20: R19 + triple-buffered LDS with DMA issued 2 ibks ahead. The per-ibk
// barrier becomes s_waitcnt vmcnt(32) + s_barrier (no drain: the buffer for
// ibk+1 was published one barrier earlier via the in-order vmcnt chain), and
// B prefetch flows through the barrier (p17 prefetches next-ibk p0 from the
// already-published next buffer) — no dist-0 reads, no post-barrier burst.

typedef __bf16 bf16x8 __attribute__((ext_vector_type(8)));
typedef float f32x16 __attribute__((ext_vector_type(16)));

#define PLANE_B  20736u                 // 324 positions * 64 B (18x18x32 bf16)
#define XH_BYTES (4096u * PLANE_B)      // 256 b * 16 icblk planes
#define OUT_HALF 16777216u              // B*CH*S
#define BUFSTEP  24576                  // LDS buffer stride

__device__ inline void gload_lds16(const void* g, void* l) {
    __builtin_amdgcn_global_load_lds(
        (const __attribute__((address_space(1))) void*)g,
        (__attribute__((address_space(3))) void*)l, 16, 0, 0);
}

// ---------------------------------------------------------------------------
// P1a: x,h (NCHW fp32) -> padded swizzled bf16 planes.
// addr = (p*64 + ofs) ^ ((p&7)<<4)  (bijective; same formula on read).
__global__ __launch_bounds__(256) void xh_transform(
    const float* __restrict__ x, const float* __restrict__ hh,
    unsigned char* __restrict__ xh)
{
    int blk = blockIdx.x;              // b*16 + ibk
    int b = blk >> 4, ibk = blk & 15;
    const float* src = (ibk < 8) ? (x  + ((size_t)(b*256 + ibk*32)) * 256)
                                 : (hh + ((size_t)(b*256 + (ibk-8)*32)) * 256);
    int t = threadIdx.x;               // t == spatial s
    uint32_t w[16];
#pragma unroll
    for (int i = 0; i < 16; ++i) {
        __bf16 lo = (__bf16)src[(size_t)(2*i  )*256 + t];
        __bf16 hi = (__bf16)src[(size_t)(2*i+1)*256 + t];
        w[i] = (uint32_t)__builtin_bit_cast(unsigned short, lo)
             | ((uint32_t)__builtin_bit_cast(unsigned short, hi) << 16);
    }
    unsigned char* plane = xh + (size_t)blk * PLANE_B;
    int p = ((t >> 4) + 1)*18 + (t & 15) + 1;      // interior position
    uint32_t key  = (uint32_t)(p & 7) << 4;
    uint32_t base = (uint32_t)p * 64u;
#pragma unroll
    for (int k = 0; k < 4; ++k)
        *(uint4*)(plane + ((base + 16u*k) ^ key)) =
            uint4{w[4*k], w[4*k+1], w[4*k+2], w[4*k+3]};
    // zero the 68 border positions (rows 0,17; cols 0,17)
    if (t < 68) {
        int pb;
        if      (t < 18) pb = t;                   // row 0
        else if (t < 36) pb = 17*18 + (t - 18);    // row 17
        else if (t < 52) pb = (t - 35)*18;         // rows 1..16, col 0
        else             pb = (t - 51)*18 + 17;    // rows 1..16, col 17
        uint32_t kb = (uint32_t)(pb & 7) << 4;
        uint32_t bb = (uint32_t)pb * 64u;
        uint4 z{0u,0u,0u,0u};
#pragma unroll
        for (int k = 0; k < 4; ++k)
            *(uint4*)(plane + ((bb + 16u*k) ^ kb)) = z;
    }
}

// ---------------------------------------------------------------------------
// P1b: Wx,Wh (OIHW fp32) -> Wt bf16 in A-fragment order.
// chunk = ((cb*16 + ibk)*9 + pos)*8 + half*4 + f ; 64 lanes x 8 bf16 each.
// Byte layout: cb*1179648 + ibk*73728 + pos*8192 + half*4096 + f*1024.
__global__ __launch_bounds__(256) void w_transform(
    const float* __restrict__ Wx, const float* __restrict__ Wh,
    __bf16* __restrict__ Wt)
{
    int idx  = blockIdx.x * 256 + threadIdx.x;   // 589824 total
    int lane = idx & 63;
    int chunk = idx >> 6;                        // 9216 chunks
    int f    = chunk & 3;
    int half = (chunk >> 2) & 1;
    int pos  = (chunk >> 3) % 9;                 // ky*3+kx
    int rest = (chunk >> 3) / 9;                 // 0..127
    int ibk  = rest & 15;
    int cb   = rest >> 4;                        // 0..7
    int row = lane & 31, hl = lane >> 5;
    int gate = row & 3, ch8 = row >> 2;
    int oc  = gate*256 + cb*32 + f*8 + ch8;
    int ic0 = ibk*32 + half*16 + hl*8;
    bf16x8 v;
#pragma unroll
    for (int j = 0; j < 8; ++j) {
        int ic = ic0 + j;
        float w = (ic < 256) ? Wx[((size_t)oc*256 + ic      )*9 + pos]
                             : Wh[((size_t)oc*256 + (ic-256))*9 + pos];
        v[j] = (__bf16)w;
    }
    *(bf16x8*)(Wt + (size_t)chunk*512 + (size_t)lane*8) = v;
}

// ---------------------------------------------------------------------------
// Main. Block = (b, cb): 256m x 128oc'. 4 waves = (wm, wf), each 128m x 64oc:
// acc[4][2] f32x16 = 128 AGPR. 18 phases/ibk; A dist-2 (%3 slots), B dist-1
// flowing through the barrier; triple-buffered LDS, DMA 2 ibks ahead,
// vmcnt(32) barrier.
__global__ __launch_bounds__(256, 2) void convlstm_main(
    const unsigned char* __restrict__ xh, const unsigned char* __restrict__ Wtb,
    const float* __restrict__ bh,  const float* __restrict__ cin,
    const float* __restrict__ Wci, const float* __restrict__ Wcf,
    const float* __restrict__ Wco, float* __restrict__ out)
{
    int bid = blockIdx.x;               // b*8 + cb
    int cb  = bid & 7;
    int b   = bid >> 3;
    int tid = threadIdx.x;
    int lane = tid & 63, wv = tid >> 6;
    int wm = wv & 1, wf = wv >> 1;
    int l31 = lane & 31, hl = lane >> 5;

    __shared__ __align__(16) unsigned char lds3[3*24576];

    // accumulators init with bias bh[oc]; wave's f-pair = wf*2 + j
    f32x16 acc[4][2];
#pragma unroll
    for (int j = 0; j < 2; ++j) {
        int fg = wf*2 + j;
        f32x16 v;
#pragma unroll
        for (int r = 0; r < 16; ++r) {
            int gate = r & 3, q = r >> 2;
            v[r] = bh[gate*256 + cb*32 + fg*8 + 2*q + hl];
        }
        acc[0][j] = v; acc[1][j] = v; acc[2][j] = v; acc[3][j] = v;
    }

    const unsigned char* planes = xh + (size_t)b * (16u * PLANE_B);

    // stage plane 0 -> buffer 0, plane 1 -> buffer 1
#pragma unroll
    for (int k = 0; k < 6; ++k) {
        gload_lds16(planes + (size_t)(wv*6 + k)*1024u + (size_t)lane*16u,
                    &lds3[(wv*6 + k)*1024 + lane*16]);
        gload_lds16(planes + PLANE_B + (size_t)(wv*6 + k)*1024u
                           + (size_t)lane*16u,
                    &lds3[BUFSTEP + (wv*6 + k)*1024 + lane*16]);
    }

    // B LDS addresses for mf=0 and mf=1 (buffer 0); mf=2/3 are +4608 literal.
    // m(mf) = wm*128 + mf*32 + l31 -> p(mf) = p(0) + 36*mf.
    // addr(mf=1) = (addr(mf=0) + 2304) ^ 64  [carry-safe: 2304 = 0x900]
    int m0 = wm*128 + l31;
    int pb0 = (m0 >> 4)*18 + (m0 & 15);
    const uint32_t kbase = (uint32_t)(hl*16);
    uint32_t baddr[9][2];
#pragma unroll
    for (int pos = 0; pos < 9; ++pos) {
        int d = (pos/3)*18 + (pos%3);
        int pp = pb0 + d;
        uint32_t a = ((uint32_t)pp*64u + kbase) ^ (((uint32_t)(pp & 7)) << 4);
        baddr[pos][0] = a;
        baddr[pos][1] = (a + 2304u) ^ 64u;
    }
    const char* lds0 = (const char*)&lds3[0];

    // A pointer: uniform base + wf f-pair + lane; phase offsets literal.
    const unsigned char* aptr = Wtb + (size_t)cb*1179648u
                                    + (size_t)(wf*2048) + (size_t)(lane*16);

    bf16x8 A[3][2], Bb[2][4];
    // A prologue: (ibk0, ph0) -> slot 0, (ibk0, ph1) -> slot 1
    A[0][0] = *(const bf16x8*)(aptr + 0);
    A[0][1] = *(const bf16x8*)(aptr + 1024);
    A[1][0] = *(const bf16x8*)(aptr + 4096);
    A[1][1] = *(const bf16x8*)(aptr + 5120);

    __syncthreads();   // prologue: one full drain (both DMA planes + joins)

    // B p0 of ibk0 (dist-0 once)
    Bb[0][0] = *(const bf16x8*)(lds0 + baddr[0][0]);
    Bb[0][1] = *(const bf16x8*)(lds0 + baddr[0][1]);
    Bb[0][2] = *(const bf16x8*)(lds0 + baddr[0][0] + 4608);
    Bb[0][3] = *(const bf16x8*)(lds0 + baddr[0][1] + 4608);

    // buffer rotation state (wave-uniform)
    int delta  = BUFSTEP;     // (ibk+1 buf offset) - (ibk buf offset)
    int bof    = 0;           // current buffer offset
    int dmaoff = 2*BUFSTEP;   // buffer offset for ibk+2 staging

// One ibk body. LAST literal gates DMA, the p17 B-prefetch, and clamps the
// cross-ibk A prefetch.
#define IBK_PHASES(LAST)                                                     \
    {                                                                        \
        _Pragma("unroll")                                                    \
        for (int p = 0; p < 18; ++p) {                                       \
            /* A prefetch dist-2 into slot (p+2)%3 */                        \
            {                                                                \
                const int tp = p + 2;                                        \
                const int off = (tp < 18)                                    \
                    ? (tp*4096)                                              \
                    : ((LAST) ? (17*4096)                 /* dummy */        \
                              : (73728 + (tp-18)*4096));                     \
                A[(p+2)%3][0] = *(const bf16x8*)(aptr + off);                \
                A[(p+2)%3][1] = *(const bf16x8*)(aptr + off + 1024);         \
            }                                                                \
            /* DMA for ibk+2 into its (long-idle) buffer */                  \
            if (p == 1 && !(LAST) && ibk <= 13) {                            \
                const unsigned char* np_ = planes + (size_t)(ibk+2)*PLANE_B; \
                _Pragma("unroll")                                            \
                for (int k = 0; k < 6; ++k)                                  \
                    gload_lds16(np_ + (size_t)(wv*6 + k)*1024u               \
                                    + (size_t)lane*16u,                      \
                                &lds3[dmaoff + (wv*6 + k)*1024 + lane*16]);  \
            }                                                                \
            /* B prefetch dist-1; at p17 cross into next buffer (published   \
               one barrier ago) for next-ibk p0 */                           \
            if (p < 17) {                                                    \
                const int np = p + 1;                                        \
                const uint32_t hx = (uint32_t)((np & 1)*32);                 \
                uint32_t a0 = baddr[np>>1][0] ^ hx;                          \
                uint32_t a1 = baddr[np>>1][1] ^ hx;                          \
                Bb[np&1][0] = *(const bf16x8*)(lds0 + a0);                   \
                Bb[np&1][1] = *(const bf16x8*)(lds0 + a1);                   \
                Bb[np&1][2] = *(const bf16x8*)(lds0 + a0 + 4608);            \
                Bb[np&1][3] = *(const bf16x8*)(lds0 + a1 + 4608);            \
            } else if (!(LAST)) {                                            \
                uint32_t a0n = baddr[0][0] + (uint32_t)delta;                \
                uint32_t a1n = baddr[0][1] + (uint32_t)delta;                \
                Bb[0][0] = *(const bf16x8*)(lds0 + a0n);                     \
                Bb[0][1] = *(const bf16x8*)(lds0 + a1n);                     \
                Bb[0][2] = *(const bf16x8*)(lds0 + a0n + 4608);              \
                Bb[0][3] = *(const bf16x8*)(lds0 + a1n + 4608);              \
            }                                                                \
            __builtin_amdgcn_s_setprio(1);                                   \
            acc[0][0] = __builtin_amdgcn_mfma_f32_32x32x16_bf16(A[p%3][0], Bb[p&1][0], acc[0][0], 0, 0, 0); \
            acc[0][1] = __builtin_amdgcn_mfma_f32_32x32x16_bf16(A[p%3][1], Bb[p&1][0], acc[0][1], 0, 0, 0); \
            acc[1][0] = __builtin_amdgcn_mfma_f32_32x32x16_bf16(A[p%3][0], Bb[p&1][1], acc[1][0], 0, 0, 0); \
            acc[1][1] = __builtin_amdgcn_mfma_f32_32x32x16_bf16(A[p%3][1], Bb[p&1][1], acc[1][1], 0, 0, 0); \
            acc[2][0] = __builtin_amdgcn_mfma_f32_32x32x16_bf16(A[p%3][0], Bb[p&1][2], acc[2][0], 0, 0, 0); \
            acc[2][1] = __builtin_amdgcn_mfma_f32_32x32x16_bf16(A[p%3][1], Bb[p&1][2], acc[2][1], 0, 0, 0); \
            acc[3][0] = __builtin_amdgcn_mfma_f32_32x32x16_bf16(A[p%3][0], Bb[p&1][3], acc[3][0], 0, 0, 0); \
            acc[3][1] = __builtin_amdgcn_mfma_f32_32x32x16_bf16(A[p%3][1], Bb[p&1][3], acc[3][1], 0, 0, 0); \
            __builtin_amdgcn_s_setprio(0);                                   \
        }                                                                    \
    }

    for (int ibk = 0; ibk < 15; ++ibk) {
        IBK_PHASES(0)
        // rotate B addresses to the next buffer; advance A base; update state
#pragma unroll
        for (int pos = 0; pos < 9; ++pos) {
            baddr[pos][0] += (uint32_t)delta;
            baddr[pos][1] += (uint32_t)delta;
        }
        aptr += 73728;
        bof += delta;
        delta  = (bof == 2*BUFSTEP) ? -(2*BUFSTEP) : BUFSTEP;
        dmaoff = (dmaoff == 2*BUFSTEP) ? 0 : dmaoff + BUFSTEP;
        // Barrier: vmcnt(32) formally publishes the buffer staged one ibk
        // ago (32 A-loads were issued after its DMA); no recent op is
        // forced — steady-state outstanding (~14) is below the bound.
        asm volatile("s_waitcnt vmcnt(32)" ::: "memory");
        __builtin_amdgcn_s_barrier();
        __builtin_amdgcn_sched_barrier(0);
    }
    {
        const int ibk = 15;
        (void)ibk;
        IBK_PHASES(1)
    }
#undef IBK_PHASES

    // fused LSTM epilogue. col = l31 (m), r = 4*q + gate,
    // ch = cb*32 + (wf*2+j)*8 + 2*q + hl ; m = wm*128 + mf*32 + l31.
    float* outh = out;
    float* outc = out + (size_t)OUT_HALF;
    const size_t bOff = (size_t)b * (256*256);
#pragma unroll
    for (int mf = 0; mf < 4; ++mf) {
        int m = wm*128 + mf*32 + l31;
#pragma unroll
        for (int j = 0; j < 2; ++j) {
            int fg = wf*2 + j;
#pragma unroll
            for (int q = 0; q < 4; ++q) {
                int ch = cb*32 + fg*8 + 2*q + hl;
                size_t pidx = (size_t)ch*256 + (size_t)m;
                size_t idx  = bOff + pidx;
                float cv = cin[idx];
                float pi = acc[mf][j][4*q+0];
                float pf = acc[mf][j][4*q+1];
                float pc = acc[mf][j][4*q+2];
                float po = acc[mf][j][4*q+3];
                float it = 1.f/(1.f + __expf(-(pi + Wci[pidx]*cv)));
                float ft = 1.f/(1.f + __expf(-(pf + Wcf[pidx]*cv)));
                float tc = 1.f - 2.f/(1.f + __expf(2.f*pc));
                float ct = ft*cv + it*tc;
                float ot = 1.f/(1.f + __expf(-(po + Wco[pidx]*ct)));
                float th = 1.f - 2.f/(1.f + __expf(2.f*ct));
                outh[idx] = ot*th;
                outc[idx] = ct;
            }
        }
    }
}

// ---------------------------------------------------------------------------
extern "C" void kernel_launch(void* const* d_in, const int* in_sizes, int n_in,
                              void* d_out, int out_size, void* d_ws, size_t ws_size,
                              hipStream_t stream)
{
    const float* x   = (const float*)d_in[0];
    const float* h   = (const float*)d_in[1];
    const float* c   = (const float*)d_in[2];
    const float* Wx  = (const float*)d_in[3];
    const float* Wh  = (const float*)d_in[4];
    const float* bh  = (const float*)d_in[5];
    const float* Wci = (const float*)d_in[6];
    const float* Wcf = (const float*)d_in[7];
    const float* Wco = (const float*)d_in[8];
    float* out = (float*)d_out;

    unsigned char* xh = (unsigned char*)d_ws;        // padded plane store
    unsigned char* wtb = xh + (size_t)XH_BYTES + 4096; // weights after slack

    hipLaunchKernelGGL(xh_transform, dim3(4096), dim3(256), 0, stream, x, h, xh);
    hipLaunchKernelGGL(w_transform,  dim3(2304), dim3(256), 0, stream,
                       Wx, Wh, (__bf16*)wtb);
    hipLaunchKernelGGL(convlstm_main, dim3(2048), dim3(256), 0, stream,
                       xh, wtb, bh, c, Wci, Wcf, Wco, out);
}